// Round 4
// baseline (89.144 us; speedup 1.0000x reference)
//
#include <hip/hip_runtime.h>
#include <math.h>

// Problem constants: B=2, T=8, NQ=128, NK=128, DIM_IN=64, DIM_OUT=256
#define C_TANH 2.8853900817779268f   // 2*log2(e): exp(2x) == exp2(C*x)
#define LOG2E  1.4426950408889634f

// Odd polynomial tanh(x) ~= u*P(u^2), u = clamp(x/R, -1, 1), degree 17.
// Coefficients are FIT ON THE HOST each launch (deterministic) and passed
// as kernel args -> land in SGPRs, broadcast free.
struct TanhPoly { float c[9]; float invR; };

// Fused projection kernel, 512 blocks x 256 threads (RAW outputs, no C fold):
//   blocks [0,256):   k2[bt][d][k] = keys[bt,k,:]@Wk[:,d] + bk[d]  (transposed)
//   blocks [256,512): q1[row][d]   = query[row,:]@Wq[:,d]
__global__ __launch_bounds__(256) void proj_kernel(
    const float* __restrict__ query, const float* __restrict__ keys,
    const float* __restrict__ Wq, const float* __restrict__ Wk,
    const float* __restrict__ bk, float* __restrict__ q1,
    float* __restrict__ k2) {
  int bid = blockIdx.x;
  int d   = threadIdx.x;
  if (bid < 256) {
    int bt = bid >> 4;
    int kg = bid & 15;
    __shared__ float4 krows4[128];  // 8 key rows x 64 floats
    if (threadIdx.x < 128)
      krows4[threadIdx.x] =
          ((const float4*)(keys + bt * 8192 + kg * 512))[threadIdx.x];
    __syncthreads();
    float acc[8];
    float bias = bk[d];
#pragma unroll
    for (int kk = 0; kk < 8; ++kk) acc[kk] = bias;
#pragma unroll 4
    for (int i4 = 0; i4 < 16; ++i4) {
      float wa = Wk[(i4 * 4 + 0) * 256 + d];
      float wb = Wk[(i4 * 4 + 1) * 256 + d];
      float wc = Wk[(i4 * 4 + 2) * 256 + d];
      float wd = Wk[(i4 * 4 + 3) * 256 + d];
#pragma unroll
      for (int kk = 0; kk < 8; ++kk) {
        float4 kr = krows4[kk * 16 + i4];  // wave-uniform b128 broadcast
        acc[kk] = fmaf(kr.x, wa, acc[kk]);
        acc[kk] = fmaf(kr.y, wb, acc[kk]);
        acc[kk] = fmaf(kr.z, wc, acc[kk]);
        acc[kk] = fmaf(kr.w, wd, acc[kk]);
      }
    }
#pragma unroll
    for (int kk = 0; kk < 8; ++kk)
      k2[(bt * 256 + d) * 128 + kg * 8 + kk] = acc[kk];
  } else {
    int row = bid - 256;
    __shared__ float qrow[64];
    if (threadIdx.x < 64) qrow[threadIdx.x] = query[row * 64 + threadIdx.x];
    __syncthreads();
    float acc = 0.f;
#pragma unroll
    for (int i = 0; i < 64; ++i) acc += qrow[i] * Wq[i * 256 + d];
    q1[row * 256 + d] = acc;
  }
}

// Score+softmax. Block = ONE row (2048 blocks -> 8 blocks/CU, 32 waves/CU).
// Wave w handles d in [w*64, w*64+64); lane = k-pair. d processed in PAIRS:
//   even d -> exact path:  acc_r += v'_d * rcp(1 + exp2(C*(q+k)))   [transc pipe]
//   odd  d -> poly path:   acc_t += v'_d * tanhpoly(q+k)            [packed VALU]
// logits = acc_t - 2*acc_r (the Sum v'_d constants drop: softmax shift-inv).
// v' = v*log2(e) so softmax runs directly in exp2 domain. The two pipes
// overlap across the 8 resident waves/SIMD -> bound = max(pipe), not sum.
__global__ __launch_bounds__(256, 8) void score_kernel(
    const float* __restrict__ q1, const float* __restrict__ v,
    const float* __restrict__ k2, float* __restrict__ out, TanhPoly tp) {
  __shared__ float2 qv[256];      // {q_raw, v*log2e} per d
  __shared__ float2 part[4][64];  // per-wave partial logit pairs
  int tid = threadIdx.x;
  int wid = tid >> 6;
  int kk  = tid & 63;             // k-pair index
  int row = blockIdx.x;           // global (b,t,q) row, 2048 total
  int bt  = row >> 7;
  int b   = row >> 10;
  int qrow = b * 128 + (row & 127);

  qv[tid] = make_float2(q1[qrow * 256 + tid], v[tid] * LOG2E);
  __syncthreads();

  const float2* kp2 = (const float2*)(k2 + bt * 32768) + kk;
  int dbase = wid * 64;
  float2 accR = make_float2(0.f, 0.f);
  float2 accT = make_float2(0.f, 0.f);
#pragma unroll 4
  for (int j = 0; j < 32; ++j) {
    int d0 = dbase + 2 * j;
    float2 qv0 = qv[d0];          // wave-uniform LDS broadcast
    float2 qv1 = qv[d0 + 1];
    float2 kv0 = kp2[d0 * 64];    // coalesced 512B wave loads
    float2 kv1 = kp2[d0 * 64 + 64];
    // --- exact path (transcendental pipe) ---
    float e0 = __builtin_amdgcn_exp2f(C_TANH * (qv0.x + kv0.x));
    float e1 = __builtin_amdgcn_exp2f(C_TANH * (qv0.x + kv0.y));
    float r0 = __builtin_amdgcn_rcpf(1.0f + e0);
    float r1 = __builtin_amdgcn_rcpf(1.0f + e1);
    accR.x = fmaf(qv0.y, r0, accR.x);
    accR.y = fmaf(qv0.y, r1, accR.y);
    // --- poly path (packed fp32 VALU pipe) ---
    float ux = (qv1.x + kv1.x) * tp.invR;
    float uy = (qv1.x + kv1.y) * tp.invR;
    ux = fminf(fmaxf(ux, -1.f), 1.f);
    uy = fminf(fmaxf(uy, -1.f), 1.f);
    float yx = ux * ux, yy = uy * uy;
    float hx = tp.c[8], hy = tp.c[8];
#pragma unroll
    for (int c = 7; c >= 0; --c) {
      hx = fmaf(hx, yx, tp.c[c]);
      hy = fmaf(hy, yy, tp.c[c]);
    }
    accT.x = fmaf(qv1.y, ux * hx, accT.x);
    accT.y = fmaf(qv1.y, uy * hy, accT.y);
  }
  float2 sv;
  sv.x = fmaf(-2.f, accR.x, accT.x);
  sv.y = fmaf(-2.f, accR.y, accT.y);
  part[wid][kk] = sv;
  __syncthreads();

  if (wid == 0) {
    float2 p0 = part[0][kk], p1 = part[1][kk], p2 = part[2][kk], p3 = part[3][kk];
    float s0 = (p0.x + p1.x) + (p2.x + p3.x);
    float s1 = (p0.y + p1.y) + (p2.y + p3.y);
    float m = fmaxf(s0, s1);
#pragma unroll
    for (int off = 32; off > 0; off >>= 1) m = fmaxf(m, __shfl_xor(m, off, 64));
    float e0 = __builtin_amdgcn_exp2f(s0 - m);
    float e1 = __builtin_amdgcn_exp2f(s1 - m);
    float ssum = e0 + e1;
#pragma unroll
    for (int off = 32; off > 0; off >>= 1) ssum += __shfl_xor(ssum, off, 64);
    float inv = __builtin_amdgcn_rcpf(ssum);
    ((float2*)(out + row * 128))[kk] = make_float2(e0 * inv, e1 * inv);
  }
}

// Host-side: least-squares fit of tanh(R*u) by odd poly u*P(u^2), deg 17,
// at 512 Chebyshev nodes (near-minimax). Deterministic -> identical every call.
static TanhPoly fit_tanh_poly() {
  const double R = 3.65;
  const int N = 512, M = 9;
  double A[M][M] = {}, bvec[M] = {};
  for (int i = 0; i < N; ++i) {
    double u = cos(M_PI * (i + 0.5) / N);
    double y = u * u;
    double f = tanh(R * u);
    double basis[M];
    double p = u;
    for (int k = 0; k < M; ++k) { basis[k] = p; p *= y; }
    for (int r = 0; r < M; ++r) {
      bvec[r] += basis[r] * f;
      for (int c = 0; c <= r; ++c) A[r][c] += basis[r] * basis[c];
    }
  }
  // Cholesky A = L L^T (SPD Gram matrix)
  double L[M][M] = {};
  for (int i = 0; i < M; ++i)
    for (int j = 0; j <= i; ++j) {
      double s = A[i][j];
      for (int k = 0; k < j; ++k) s -= L[i][k] * L[j][k];
      if (i == j) L[i][i] = sqrt(s);
      else        L[i][j] = s / L[j][j];
    }
  double yv[M], x[M];
  for (int i = 0; i < M; ++i) {
    double s = bvec[i];
    for (int k = 0; k < i; ++k) s -= L[i][k] * yv[k];
    yv[i] = s / L[i][i];
  }
  for (int i = M - 1; i >= 0; --i) {
    double s = yv[i];
    for (int k = i + 1; k < M; ++k) s -= L[k][i] * x[k];
    x[i] = s / L[i][i];
  }
  TanhPoly tp;
  for (int i = 0; i < M; ++i) tp.c[i] = (float)x[i];
  tp.invR = (float)(1.0 / R);
  return tp;
}

extern "C" void kernel_launch(void* const* d_in, const int* in_sizes, int n_in,
                              void* d_out, int out_size, void* d_ws, size_t ws_size,
                              hipStream_t stream) {
  const float* query = (const float*)d_in[0];  // [2,128,64]
  const float* keys  = (const float*)d_in[1];  // [2,8,128,64]
  const float* Wq    = (const float*)d_in[2];  // [64,256]
  const float* Wk    = (const float*)d_in[3];  // [64,256]
  const float* bk    = (const float*)d_in[4];  // [256]
  const float* v     = (const float*)d_in[5];  // [256]
  float* out = (float*)d_out;                  // [2,8,128,128]

  float* ws = (float*)d_ws;
  float* q1 = ws;            // 256*256    = 65536 floats
  float* k2 = ws + 65536;    // 16*256*128 = 524288 floats

  TanhPoly tp = fit_tanh_poly();  // pure CPU, deterministic, ~40K flops

  proj_kernel<<<512, 256, 0, stream>>>(query, keys, Wq, Wk, bk, q1, k2);
  score_kernel<<<2048, 256, 0, stream>>>(q1, v, k2, out, tp);
}

// Round 5
// 88.199 us; speedup vs baseline: 1.0107x; 1.0107x over previous
//
#include <hip/hip_runtime.h>

// Problem constants: B=2, T=8, NQ=128, NK=128, DIM_IN=64, DIM_OUT=256
#define C_TANH 2.8853900817779268f   // 2*log2(e): exp(2x) == exp2(C*x)
#define LOG2E  1.4426950408889634f

// Exact f32 tanh via exp2+rcp (2 transc ops) — used only in proj (1M evals).
__device__ __forceinline__ float tanh_exact(float x) {
  float e = __builtin_amdgcn_exp2f(C_TANH * x);
  return 1.0f - 2.0f * __builtin_amdgcn_rcpf(1.0f + e);
}

// Fused projection kernel, 512 blocks x 256 threads. Outputs are TANH of the
// projections (enables the addition formula in the score kernel):
//   blocks [0,256):   k2t[bt][d][k] = tanh(keys[bt,k,:]@Wk[:,d] + bk[d])
//   blocks [256,512): q1t[row][d]   = tanh(query[row,:]@Wq[:,d])
__global__ __launch_bounds__(256) void proj_kernel(
    const float* __restrict__ query, const float* __restrict__ keys,
    const float* __restrict__ Wq, const float* __restrict__ Wk,
    const float* __restrict__ bk, float* __restrict__ q1t,
    float* __restrict__ k2t) {
  int bid = blockIdx.x;
  int d   = threadIdx.x;
  if (bid < 256) {
    int bt = bid >> 4;
    int kg = bid & 15;
    __shared__ float4 krows4[128];  // 8 key rows x 64 floats
    if (threadIdx.x < 128)
      krows4[threadIdx.x] =
          ((const float4*)(keys + bt * 8192 + kg * 512))[threadIdx.x];
    __syncthreads();
    float acc[8];
    float bias = bk[d];
#pragma unroll
    for (int kk = 0; kk < 8; ++kk) acc[kk] = bias;
#pragma unroll 4
    for (int i4 = 0; i4 < 16; ++i4) {
      float wa = Wk[(i4 * 4 + 0) * 256 + d];   // coalesced across lanes
      float wb = Wk[(i4 * 4 + 1) * 256 + d];
      float wc = Wk[(i4 * 4 + 2) * 256 + d];
      float wd = Wk[(i4 * 4 + 3) * 256 + d];
#pragma unroll
      for (int kk = 0; kk < 8; ++kk) {
        float4 kr = krows4[kk * 16 + i4];      // wave-uniform b128 broadcast
        acc[kk] = fmaf(kr.x, wa, acc[kk]);
        acc[kk] = fmaf(kr.y, wb, acc[kk]);
        acc[kk] = fmaf(kr.z, wc, acc[kk]);
        acc[kk] = fmaf(kr.w, wd, acc[kk]);
      }
    }
#pragma unroll
    for (int kk = 0; kk < 8; ++kk)
      k2t[(bt * 256 + d) * 128 + kg * 8 + kk] = tanh_exact(acc[kk]);
  } else {
    int row = bid - 256;
    __shared__ float qrow[64];
    if (threadIdx.x < 64) qrow[threadIdx.x] = query[row * 64 + threadIdx.x];
    __syncthreads();
    float acc = 0.f;
#pragma unroll
    for (int i = 0; i < 64; ++i) acc += qrow[i] * Wq[i * 256 + d];
    q1t[row * 256 + d] = tanh_exact(acc);
  }
}

// Score+softmax via tanh addition formula:
//   tanh(q+k) = (ta + tb) / (1 + ta*tb),   ta=tanh(q), tb=tanh(k)  [1 rcp/elem]
// logits'_k = sum_d v'_d * r_dk, v' = v*log2e -> softmax directly in exp2.
// Block = 4 rows of one bt (512 blocks); wave = one full row (lane = k-pair).
// tb slice [256][128] is consumed from LDS in 4 phases of [64][128] (32 KB),
// cutting k2t global traffic 268 MB -> 64 MB (tile reused by 4 rows).
// LDS/block = 32 KB tb + 8 KB qv = 40 KB -> 4 blocks/CU = 16 waves/CU.
__global__ __launch_bounds__(256, 4) void score_kernel(
    const float* __restrict__ q1t, const float* __restrict__ v,
    const float* __restrict__ k2t, float* __restrict__ out) {
  __shared__ float  tb[64 * 128];   // 32 KB: current d-quarter of the k-slice
  __shared__ float2 qv[4 * 256];    // 8 KB: {ta, v*log2e} for the 4 rows
  int tid = threadIdx.x;
  int wid = tid >> 6;               // wave = row 0..3
  int kk  = tid & 63;               // k-pair index
  int blk = blockIdx.x;             // 512 blocks = 16 bt x 32 row-groups
  int bt  = blk >> 5;
  int qg  = blk & 31;               // group of 4 q-rows
  int b   = bt >> 3;
  int q0  = qg * 4;                 // base q within [0,128)

  // stage {ta, v'}: 4 rows x 256, coalesced (4 entries/thread)
  for (int i = tid; i < 1024; i += 256) {
    int rr = i >> 8;
    int d  = i & 255;
    qv[i] = make_float2(q1t[(b * 128 + q0 + rr) * 256 + d], v[d] * LOG2E);
  }

  const float* ksrc = k2t + bt * 32768;  // [256][128] tb slice for this bt
  float2 acc = make_float2(0.f, 0.f);

#pragma unroll
  for (int h = 0; h < 4; ++h) {
    __syncthreads();  // previous phase fully consumed before overwrite
    // stage 8192 floats (32 KB) coalesced: 8 float4 per thread
    const float4* src4 = (const float4*)(ksrc + h * 8192);
    float4* dst4 = (float4*)tb;
    for (int i = tid; i < 2048; i += 256) dst4[i] = src4[i];
    __syncthreads();

    const float2* tb2 = (const float2*)tb;  // [64 d][64 k-pairs]
#pragma unroll 8
    for (int d = 0; d < 64; ++d) {
      float2 tav = qv[wid * 256 + h * 64 + d];  // wave-uniform b64 broadcast
      float2 tbv = tb2[d * 64 + kk];            // per-lane b64
      float n0 = tav.x + tbv.x;                 // numerator ta+tb
      float n1 = tav.x + tbv.y;
      float d0 = fmaf(tav.x, tbv.x, 1.0f);      // denominator 1+ta*tb >= 0.01
      float d1 = fmaf(tav.x, tbv.y, 1.0f);
      float r0 = n0 * __builtin_amdgcn_rcpf(d0);
      float r1 = n1 * __builtin_amdgcn_rcpf(d1);
      acc.x = fmaf(tav.y, r0, acc.x);
      acc.y = fmaf(tav.y, r1, acc.y);
    }
  }

  // softmax: whole row lives in this wave -> pure 64-lane butterfly
  float s0 = acc.x, s1 = acc.y;     // logits pre-scaled by log2(e)
  float m = fmaxf(s0, s1);
#pragma unroll
  for (int off = 32; off > 0; off >>= 1) m = fmaxf(m, __shfl_xor(m, off, 64));
  float e0 = __builtin_amdgcn_exp2f(s0 - m);
  float e1 = __builtin_amdgcn_exp2f(s1 - m);
  float ssum = e0 + e1;
#pragma unroll
  for (int off = 32; off > 0; off >>= 1) ssum += __shfl_xor(ssum, off, 64);
  float inv = __builtin_amdgcn_rcpf(ssum);

  int row = bt * 128 + q0 + wid;    // output row
  ((float2*)(out + row * 128))[kk] = make_float2(e0 * inv, e1 * inv);
}

extern "C" void kernel_launch(void* const* d_in, const int* in_sizes, int n_in,
                              void* d_out, int out_size, void* d_ws, size_t ws_size,
                              hipStream_t stream) {
  const float* query = (const float*)d_in[0];  // [2,128,64]
  const float* keys  = (const float*)d_in[1];  // [2,8,128,64]
  const float* Wq    = (const float*)d_in[2];  // [64,256]
  const float* Wk    = (const float*)d_in[3];  // [64,256]
  const float* bk    = (const float*)d_in[4];  // [256]
  const float* v     = (const float*)d_in[5];  // [256]
  float* out = (float*)d_out;                  // [2,8,128,128]

  float* ws  = (float*)d_ws;
  float* q1t = ws;            // 256*256    = 65536 floats (tanh of q-proj)
  float* k2t = ws + 65536;    // 16*256*128 = 524288 floats (tanh of k-proj)

  proj_kernel<<<512, 256, 0, stream>>>(query, keys, Wq, Wk, bk, q1t, k2t);
  score_kernel<<<512, 256, 0, stream>>>(q1t, v, k2t, out);
}